// Round 1
// baseline (171.917 us; speedup 1.0000x reference)
//
#include <hip/hip_runtime.h>

#define IN_F 4096
#define OUT_F 16384

typedef __bf16 bf16x8 __attribute__((ext_vector_type(8)));
typedef float f32x4 __attribute__((ext_vector_type(4)));
typedef int i32x4 __attribute__((ext_vector_type(4)));
typedef unsigned short u16x4 __attribute__((ext_vector_type(4)));

__device__ __forceinline__ unsigned short f2bf_rne(float f) {
    unsigned int u = __float_as_uint(f);
    u += 0x7FFFu + ((u >> 16) & 1u);
    return (unsigned short)(u >> 16);
}
__device__ __forceinline__ unsigned short i2bf(int v) {
    // exact for |v| <= 255 (int -> float -> truncate top 16 bits, low bits are 0)
    return (unsigned short)(__float_as_uint((float)v) >> 16);
}

#define BM 128
#define BN 128
#define BK 64

__global__ __launch_bounds__(256, 2)
void qgemm_kernel(const float* __restrict__ x, const int* __restrict__ Wq,
                  const float* __restrict__ scales, const float* __restrict__ bias,
                  float* __restrict__ out) {
    __shared__ __align__(16) unsigned char sA[BM * BK * 2];  // 16 KB bf16, swizzled
    __shared__ __align__(16) unsigned char sB[BN * BK * 2];  // 16 KB bf16, swizzled

    // ---- tile mapping: mt-inner (Wq panel reuse) + XCD-chunked swizzle ----
    // grid = 512 = 4 mtiles * 128 ntiles; 512 % 8 == 0 -> simple swizzle bijective
    const int bid = (int)blockIdx.x;
    const int g = (bid & 7) * 64 + (bid >> 3);   // same-XCD blocks contiguous in g
    const int mt = g & 3;                         // 4 M tiles (inner: share Wq panel)
    const int nt = g >> 2;                        // 128 N tiles
    const int brow = mt * BM;
    const int bcol = nt * BN;

    const int t = (int)threadIdx.x;  // 0..255
    const int lane = t & 63;
    const int wid = t >> 6;          // 4 waves
    const int wr = wid >> 1;         // wave row 0..1 (64 rows each)
    const int wc = wid & 1;          // wave col 0..1 (64 cols each)

    // ---- staging decomposition: 8192 elems / 256 thr = 8x float4 per matrix ----
    const int srow = t >> 4;         // 0..15 (advances by 16 per i)
    const int sc4 = t & 15;          // float4 index within BK=64 row segment

    const float* xg = x + (size_t)(brow + srow) * IN_F + sc4 * 4;
    const int* wg = Wq + (size_t)(bcol + srow) * IN_F + sc4 * 4;

    f32x4 acc[4][4];
#pragma unroll
    for (int i = 0; i < 4; ++i)
#pragma unroll
        for (int j = 0; j < 4; ++j) {
            f32x4 z = {0.f, 0.f, 0.f, 0.f};
            acc[i][j] = z;
        }

    const int frow_a = wr * 64 + (lane & 15);
    const int frow_b = wc * 64 + (lane & 15);
    const int fk = (lane >> 4) * 16;  // byte offset of this lane's 8 bf16 (k dim)

#pragma unroll 1
    for (int kt = 0; kt < IN_F / BK; ++kt) {
        const int k0 = kt * BK;

        // global loads first (issue before barrier; waitcnt lands after it)
        f32x4 av[8];
        i32x4 bv[8];
#pragma unroll
        for (int i = 0; i < 8; ++i) {
            av[i] = *(const f32x4*)(xg + k0 + i * 16 * IN_F);
            bv[i] = *(const i32x4*)(wg + k0 + i * 16 * IN_F);
        }

        __syncthreads();  // previous iteration's ds_reads complete

#pragma unroll
        for (int i = 0; i < 8; ++i) {
            const int row = srow + i * 16;
            unsigned off = (unsigned)(row * 128 + sc4 * 8);
            off ^= (unsigned)(row & 7) << 4;  // bank-conflict swizzle (G4)
            u16x4 pa, pb;
            pa.x = f2bf_rne(av[i].x); pa.y = f2bf_rne(av[i].y);
            pa.z = f2bf_rne(av[i].z); pa.w = f2bf_rne(av[i].w);
            pb.x = i2bf(bv[i].x); pb.y = i2bf(bv[i].y);
            pb.z = i2bf(bv[i].z); pb.w = i2bf(bv[i].w);
            *(u16x4*)(sA + off) = pa;
            *(u16x4*)(sB + off) = pb;
        }

        __syncthreads();

#pragma unroll
        for (int ks = 0; ks < 2; ++ks) {
            bf16x8 af[4], bf[4];
#pragma unroll
            for (int m = 0; m < 4; ++m) {
                const int row = frow_a + m * 16;
                unsigned off = (unsigned)(row * 128 + ks * 64 + fk);
                off ^= (unsigned)(row & 7) << 4;
                af[m] = *(const bf16x8*)(sA + off);
            }
#pragma unroll
            for (int n = 0; n < 4; ++n) {
                const int row = frow_b + n * 16;
                unsigned off = (unsigned)(row * 128 + ks * 64 + fk);
                off ^= (unsigned)(row & 7) << 4;
                bf[n] = *(const bf16x8*)(sB + off);
            }
#pragma unroll
            for (int m = 0; m < 4; ++m)
#pragma unroll
                for (int n = 0; n < 4; ++n)
                    acc[m][n] = __builtin_amdgcn_mfma_f32_16x16x32_bf16(
                        af[m], bf[n], acc[m][n], 0, 0, 0);
        }
    }

    // ---- epilogue: dequant scale (per output col) + bias, fp32 store ----
    // C/D layout (m89-verified): col = lane&15, row = (lane>>4)*4 + reg
    const int orow = brow + wr * 64 + ((lane >> 4) << 2);
    const int ocol = bcol + wc * 64 + (lane & 15);
#pragma unroll
    for (int n = 0; n < 4; ++n) {
        const int c = ocol + n * 16;
        const float sc = scales[c];
        const float bs = bias[c];
#pragma unroll
        for (int m = 0; m < 4; ++m) {
            const int r = orow + m * 16;
            float* po = out + (size_t)r * OUT_F + c;
#pragma unroll
            for (int j = 0; j < 4; ++j) {
                po[(size_t)j * OUT_F] = acc[m][n][j] * sc + bs;
            }
        }
    }
}

extern "C" void kernel_launch(void* const* d_in, const int* in_sizes, int n_in,
                              void* d_out, int out_size, void* d_ws, size_t ws_size,
                              hipStream_t stream) {
    const float* x = (const float*)d_in[0];
    const int* Wq = (const int*)d_in[1];
    const float* scales = (const float*)d_in[2];
    const float* bias = (const float*)d_in[3];
    float* out = (float*)d_out;

    dim3 grid(512);   // 4 mtiles * 128 ntiles
    dim3 block(256);  // 4 waves
    hipLaunchKernelGGL(qgemm_kernel, grid, block, 0, stream, x, Wq, scales, bias, out);
}

// Round 2
// 115.193 us; speedup vs baseline: 1.4924x; 1.4924x over previous
//
#include <hip/hip_runtime.h>

#define IN_F 4096
#define OUT_F 16384
#define M_ROWS 512

#define BM 256
#define BN 128
#define BK 64
#define NKT (IN_F / BK)  // 64
#define THREADS 512

typedef __bf16 bf16x8_t __attribute__((ext_vector_type(8)));
typedef __bf16 bf16x4_t __attribute__((ext_vector_type(4)));
typedef float f32x4_t __attribute__((ext_vector_type(4)));
typedef int i32x4_t __attribute__((ext_vector_type(4)));

__device__ __forceinline__ void gld16(const void* g, void* l) {
    __builtin_amdgcn_global_load_lds(
        (const __attribute__((address_space(1))) void*)g,
        (__attribute__((address_space(3))) void*)l,
        16 /*bytes, literal*/, 0, 0);
}

// ---------------- pre-pass: x fp32 -> bf16 in inverse-swizzled tile layout --------------
// ws tile t = mt*64+kt holds a 256x64 panel as the exact byte image the GEMM's
// global_load_lds drops into LDS. GEMM reads elem (row,col) at LDS byte
// (row*128 + col*2) ^ ((row&7)<<4), so ws linear slot (row,rem) must hold
// x[row][col = rem ^ ((row&7)<<3)].
__global__ __launch_bounds__(256)
void xpack_kernel(const float* __restrict__ x, __bf16* __restrict__ xp) {
    const int tid = blockIdx.x * 256 + (int)threadIdx.x;  // 262144 threads
    const int e0 = tid * 8;
    const int tile = e0 >> 14;        // /16384 elems per tile
    const int within = e0 & 16383;
    const int row = within >> 6;
    const int rem0 = within & 63;     // multiple of 8
    const int mt = tile >> 6;
    const int kt = tile & 63;
    const int grow = mt * 256 + row;
    const int gcol = kt * 64 + (rem0 ^ ((row & 7) << 3));  // stays a multiple of 8
    const float* src = x + (size_t)grow * IN_F + gcol;
    f32x4_t a = *(const f32x4_t*)(src);
    f32x4_t b = *(const f32x4_t*)(src + 4);
    bf16x8_t o;
    o[0] = (__bf16)a[0]; o[1] = (__bf16)a[1]; o[2] = (__bf16)a[2]; o[3] = (__bf16)a[3];
    o[4] = (__bf16)b[0]; o[5] = (__bf16)b[1]; o[6] = (__bf16)b[2]; o[7] = (__bf16)b[3];
    *(bf16x8_t*)(xp + e0) = o;
}

// ---------------- main GEMM ----------------
template <bool PRE>
__global__ __launch_bounds__(THREADS, 2)
void qgemm2_kernel(const float* __restrict__ x, const __bf16* __restrict__ xp,
                   const int* __restrict__ Wq,
                   const float* __restrict__ scales, const float* __restrict__ bias,
                   float* __restrict__ out) {
    __shared__ __align__(16) unsigned char sA[2][BM * BK * 2];  // 2 x 32 KB, dbuf
    __shared__ __align__(16) unsigned char sB[BN * BK * 2];     // 16 KB

    const int bid = (int)blockIdx.x;
    const int g = (bid & 7) * 32 + (bid >> 3);  // XCD swizzle, 256%8==0 bijective
    const int mt = g & 1;                       // mt inner: neighbor blocks share Wq panel
    const int nt = g >> 1;
    const int brow = mt * BM;
    const int bcol = nt * BN;

    const int t = (int)threadIdx.x;
    const int lane = t & 63;
    const int wid = t >> 6;    // 8 waves
    const int wr = wid >> 1;   // 0..3  (64-row stripe)
    const int wc = wid & 1;    // 0..1  (64-col stripe)

    // ---- B staging: 128x64 int32 = 32KB = 512thr x 4 x i32x4 ----
    const int srowB = t >> 4;            // 0..31, +32 per issue
    const int scolB = (t & 15) * 4;      // elem col
    const int* wg = Wq + (size_t)(bcol + srowB) * IN_F + scolB;
    const int swzB = (srowB & 7) << 4;
    const int offB0 = srowB * 128 + ((scolB * 2) ^ swzB);

    // ---- A fallback staging (fp32 x): 256x64 = 64KB = 512thr x 8 x f32x4 ----
    const float* xg = x + (size_t)(brow + srowB) * IN_F + scolB;

    // ---- A via global_load_lds from pre-swizzled ws ----
    const __bf16* xt = xp + (size_t)(mt * NKT) * (BM * BK);  // + kt*16384
    const int ldsAoff = wid * 1024;  // wave-uniform; +i*8192 per issue

    f32x4_t acc[4][4];
#pragma unroll
    for (int i = 0; i < 4; ++i)
#pragma unroll
        for (int j = 0; j < 4; ++j) {
            f32x4_t z = {0.f, 0.f, 0.f, 0.f};
            acc[i][j] = z;
        }

    const int arow = wr * 64 + (lane & 15);
    const int brow_f = wc * 64 + (lane & 15);
    const int kb = (lane >> 4) * 16;  // byte offset of lane's 8 bf16 in k

    i32x4_t bv0[4], bv1[4];
    f32x4_t av0[8], av1[8];  // only live if !PRE

#define ISSUE_B(kt_, bvs)                                      \
    do {                                                       \
        const int* p_ = wg + (size_t)(kt_)*BK;                 \
        bvs[0] = *(const i32x4_t*)(p_);                        \
        bvs[1] = *(const i32x4_t*)(p_ + (size_t)32 * IN_F);    \
        bvs[2] = *(const i32x4_t*)(p_ + (size_t)64 * IN_F);    \
        bvs[3] = *(const i32x4_t*)(p_ + (size_t)96 * IN_F);    \
    } while (0)

#define ISSUE_A_GLD(kt_, pb)                                       \
    do {                                                           \
        const __bf16* s_ = xt + (size_t)(kt_) * (BM * BK) + t * 8; \
        unsigned char* d_ = &sA[pb][0] + ldsAoff;                  \
        gld16(s_, d_);                                             \
        gld16(s_ + 4096, d_ + 8192);                               \
        gld16(s_ + 8192, d_ + 16384);                              \
        gld16(s_ + 12288, d_ + 24576);                             \
    } while (0)

#define ISSUE_A_REG(kt_, avs)                                   \
    do {                                                        \
        const float* p_ = xg + (size_t)(kt_)*BK;                \
        _Pragma("unroll") for (int i_ = 0; i_ < 8; ++i_)        \
            avs[i_] = *(const f32x4_t*)(p_ + (size_t)i_ * 32 * IN_F); \
    } while (0)

#define WRITE_B(bvs)                                            \
    do {                                                        \
        _Pragma("unroll") for (int i_ = 0; i_ < 4; ++i_) {      \
            bf16x4_t pb_;                                       \
            pb_[0] = (__bf16)(float)bvs[i_][0];                 \
            pb_[1] = (__bf16)(float)bvs[i_][1];                 \
            pb_[2] = (__bf16)(float)bvs[i_][2];                 \
            pb_[3] = (__bf16)(float)bvs[i_][3];                 \
            *(bf16x4_t*)(sB + offB0 + i_ * 4096) = pb_;         \
        }                                                       \
    } while (0)

#define WRITE_A(avs)                                            \
    do {                                                        \
        _Pragma("unroll") for (int i_ = 0; i_ < 8; ++i_) {      \
            bf16x4_t pa_;                                       \
            pa_[0] = (__bf16)avs[i_][0];                        \
            pa_[1] = (__bf16)avs[i_][1];                        \
            pa_[2] = (__bf16)avs[i_][2];                        \
            pa_[3] = (__bf16)avs[i_][3];                        \
            *(bf16x4_t*)(&sA[pb_w][0] + offB0 + i_ * 4096) = pa_; \
        }                                                       \
    } while (0)

#define COMPUTE(pb)                                                              \
    do {                                                                         \
        _Pragma("unroll") for (int ks_ = 0; ks_ < 2; ++ks_) {                    \
            bf16x8_t af_[4], bf_[4];                                             \
            _Pragma("unroll") for (int m_ = 0; m_ < 4; ++m_) {                   \
                const int r_ = arow + m_ * 16;                                   \
                af_[m_] = *(const bf16x8_t*)(&sA[pb][0] + r_ * 128 +             \
                                             ((ks_ * 64 + kb) ^ ((r_ & 7) << 4))); \
            }                                                                    \
            _Pragma("unroll") for (int n_ = 0; n_ < 4; ++n_) {                   \
                const int r_ = brow_f + n_ * 16;                                 \
                bf_[n_] = *(const bf16x8_t*)(sB + r_ * 128 +                     \
                                             ((ks_ * 64 + kb) ^ ((r_ & 7) << 4))); \
            }                                                                    \
            _Pragma("unroll") for (int m_ = 0; m_ < 4; ++m_)                     \
                _Pragma("unroll") for (int n_ = 0; n_ < 4; ++n_)                 \
                    acc[m_][n_] = __builtin_amdgcn_mfma_f32_16x16x32_bf16(       \
                        af_[m_], bf_[n_], acc[m_][n_], 0, 0, 0);                 \
        }                                                                        \
    } while (0)

#define WAIT_AND_BAR()                                                 \
    do {                                                               \
        if constexpr (PRE) {                                           \
            asm volatile("s_waitcnt vmcnt(8) lgkmcnt(0)" ::: "memory"); \
        } else {                                                       \
            asm volatile("s_waitcnt lgkmcnt(0)" ::: "memory");         \
        }                                                              \
        __builtin_amdgcn_sched_barrier(0);                             \
        __builtin_amdgcn_s_barrier();                                  \
        __builtin_amdgcn_sched_barrier(0);                             \
    } while (0)

    // -------- prologue: tile 0 in flight --------
    ISSUE_B(0, bv0);
    if constexpr (PRE) {
        ISSUE_A_GLD(0, 0);
    } else {
        ISSUE_A_REG(0, av0);
    }

#pragma unroll 1
    for (int kt = 0; kt < NKT; kt += 2) {
        const int kn1 = (kt + 1 < NKT) ? kt + 1 : NKT - 1;  // clamp keeps vmcnt count stable
        const int kn2 = (kt + 2 < NKT) ? kt + 2 : NKT - 1;

        // ---- sub-iter even: consume set0/buf0, prefetch set1/buf1 ----
        ISSUE_B(kn1, bv1);
        __builtin_amdgcn_s_barrier();  // all waves done reading sA[1]/sB (prev iter)
        __builtin_amdgcn_sched_barrier(0);
        if constexpr (PRE) {
            ISSUE_A_GLD(kn1, 1);
        } else {
            ISSUE_A_REG(kn1, av1);
        }
        {
            const int pb_w = 0;
            (void)pb_w;
            WRITE_B(bv0);
            if constexpr (!PRE) WRITE_A(av0);
        }
        WAIT_AND_BAR();
        COMPUTE(0);

        // ---- sub-iter odd: consume set1/buf1, prefetch set0/buf0 ----
        ISSUE_B(kn2, bv0);
        __builtin_amdgcn_s_barrier();
        __builtin_amdgcn_sched_barrier(0);
        if constexpr (PRE) {
            ISSUE_A_GLD(kn2, 0);
        } else {
            ISSUE_A_REG(kn2, av0);
        }
        {
            const int pb_w = 1;
            (void)pb_w;
            WRITE_B(bv1);
            if constexpr (!PRE) WRITE_A(av1);
        }
        WAIT_AND_BAR();
        COMPUTE(1);
    }

    // -------- epilogue: per-col dequant scale + bias, fp32 store --------
    // C/D layout: col = lane&15, row = (lane>>4)*4 + reg  (m89-verified)
    const int orow = brow + wr * 64 + ((lane >> 4) << 2);
    const int ocol = bcol + wc * 64 + (lane & 15);
#pragma unroll
    for (int n = 0; n < 4; ++n) {
        const int c = ocol + n * 16;
        const float sc = scales[c];
        const float bs = bias[c];
#pragma unroll
        for (int m = 0; m < 4; ++m) {
            const int r = orow + m * 16;
            float* po = out + (size_t)r * OUT_F + c;
#pragma unroll
            for (int j = 0; j < 4; ++j) {
                po[(size_t)j * OUT_F] = acc[m][n][j] * sc + bs;
            }
        }
    }
#undef ISSUE_B
#undef ISSUE_A_GLD
#undef ISSUE_A_REG
#undef WRITE_B
#undef WRITE_A
#undef COMPUTE
#undef WAIT_AND_BAR
}

extern "C" void kernel_launch(void* const* d_in, const int* in_sizes, int n_in,
                              void* d_out, int out_size, void* d_ws, size_t ws_size,
                              hipStream_t stream) {
    const float* x = (const float*)d_in[0];
    const int* Wq = (const int*)d_in[1];
    const float* scales = (const float*)d_in[2];
    const float* bias = (const float*)d_in[3];
    float* out = (float*)d_out;

    const size_t xp_bytes = (size_t)M_ROWS * IN_F * 2;  // 4 MB
    const bool pre = (ws_size >= xp_bytes) && (d_ws != nullptr);

    if (pre) {
        __bf16* xp = (__bf16*)d_ws;
        xpack_kernel<<<dim3((M_ROWS * IN_F / 8) / 256), dim3(256), 0, stream>>>(x, xp);
        qgemm2_kernel<true><<<dim3(256), dim3(THREADS), 0, stream>>>(
            x, xp, Wq, scales, bias, out);
    } else {
        qgemm2_kernel<false><<<dim3(256), dim3(THREADS), 0, stream>>>(
            x, (const __bf16*)nullptr, Wq, scales, bias, out);
    }
}